// Round 1
// baseline (1994.552 us; speedup 1.0000x reference)
//
#include <hip/hip_runtime.h>
#include <math.h>

// ---------------- model dims ----------------
constexpr int N_NODES = 16384;
constexpr int BGRAPH  = 64;
constexpr int NPG     = 256;
constexpr int NEDGE   = 524288;
constexpr int SEQ     = 257;           // NPG + cls
constexpr int WDIM    = 256;
constexpr int HEADS   = 8;
constexpr int DH      = 32;
constexpr int DFF     = 1024;
constexpr int HID     = 512;
constexpr int OUTD    = 64;
constexpr int MROWS   = BGRAPH * SEQ;  // 16448

// ---------------- ws layout (float offsets) ----------------
constexpr size_t F_Y    = 0;                                   // [N,64] dinv-scaled padded xc
constexpr size_t F_AGG  = F_Y    + (size_t)N_NODES * 64;       // [N,64]
constexpr size_t F_XD   = F_AGG  + (size_t)N_NODES * 64;       // [16448,256] residual stream
constexpr size_t F_H1   = F_XD   + (size_t)MROWS * WDIM;       // [16448,256] post-LN
constexpr size_t F_QKV  = F_H1   + (size_t)MROWS * WDIM;       // [16448,768]
constexpr size_t F_FFB  = F_QKV  + (size_t)MROWS * 3 * WDIM;   // [16448,1024]; scores alias here
constexpr size_t F_CLS  = F_FFB  + (size_t)MROWS * DFF;        // [64,256]
constexpr size_t F_D1   = F_CLS  + (size_t)BGRAPH * WDIM;      // [64,512]
constexpr size_t F_D2   = F_D1   + (size_t)BGRAPH * HID;       // [64,512]
constexpr size_t F_WPAD = F_D2   + (size_t)BGRAPH * HID;       // [64,256] zero-padded gcn_w
constexpr size_t F_DINV = F_WPAD + (size_t)64 * WDIM;          // [N]
constexpr size_t F_END  = F_DINV + (size_t)N_NODES;

__device__ __forceinline__ float gelu_f(float x) {
    float u = 0.7978845608028654f * (x + 0.044715f * x * x * x);
    return 0.5f * x * (1.0f + tanhf(u));
}

// ---------------- GCN prelude ----------------
__global__ __launch_bounds__(256) void hist_kernel(const int* __restrict__ col, int* __restrict__ indeg) {
    int e = blockIdx.x * 256 + threadIdx.x;
    atomicAdd(&indeg[col[e]], 1);
}

__global__ __launch_bounds__(1024) void scan_kernel(const int* __restrict__ indeg, int* __restrict__ offs,
                                                    int* __restrict__ cursor, float* __restrict__ dinv) {
    __shared__ int parts[1024];
    int t = threadIdx.x;
    int base = t * 16;
    int loc[16];
    int s = 0;
#pragma unroll
    for (int i = 0; i < 16; ++i) { loc[i] = indeg[base + i]; s += loc[i]; }
    parts[t] = s;
    __syncthreads();
    for (int off = 1; off < 1024; off <<= 1) {
        int v = (t >= off) ? parts[t - off] : 0;
        __syncthreads();
        parts[t] += v;
        __syncthreads();
    }
    int run = (t == 0) ? 0 : parts[t - 1];
#pragma unroll
    for (int i = 0; i < 16; ++i) {
        offs[base + i] = run;
        cursor[base + i] = run;
        dinv[base + i] = rsqrtf((float)loc[i] + 1.0f);  // deg = indeg + self-loop
        run += loc[i];
    }
    if (t == 1023) offs[N_NODES] = run;
}

__global__ __launch_bounds__(256) void fill_kernel(const int* __restrict__ ei, int* __restrict__ cursor,
                                                   int* __restrict__ csr) {
    int e = blockIdx.x * 256 + threadIdx.x;
    int r = ei[e];            // source
    int c = ei[NEDGE + e];    // destination
    int pos = atomicAdd(&cursor[c], 1);
    csr[pos] = r;
}

// xc = [x(32) | sin(p*2^j*pi)(24) | 0(8)], pre-scaled by dinv[node]
__global__ __launch_bounds__(256) void y_kernel(const float* __restrict__ x, const float* __restrict__ p,
                                                const float* __restrict__ dinv, float* __restrict__ y) {
    int idx = blockIdx.x * 256 + threadIdx.x;
    int i = idx >> 6, d = idx & 63;
    float v = 0.f;
    if (d < 32) {
        v = x[i * 32 + d];
    } else if (d < 56) {
        int dd = d - 32;
        int dim = dd >> 3, j = dd & 7;
        v = sinf(p[i * 3 + dim] * (3.14159265358979323846f * (float)(1 << j)));
    }
    y[idx] = dinv[i] * v;
}

// agg[c] = dinv[c] * (y[c] + sum_{in-edges} y[src])   (wave per node)
__global__ __launch_bounds__(256) void agg_kernel(const float* __restrict__ y, const float* __restrict__ dinv,
                                                  const int* __restrict__ offs, const int* __restrict__ csr,
                                                  float* __restrict__ agg) {
    int c = (blockIdx.x * 256 + threadIdx.x) >> 6;
    int lane = threadIdx.x & 63;
    float acc = y[(size_t)c * 64 + lane];
    int s = offs[c], e = offs[c + 1];
    for (int j = s; j < e; ++j) {
        int r = csr[j];
        acc += y[(size_t)r * 64 + lane];
    }
    agg[(size_t)c * 64 + lane] = dinv[c] * acc;
}

__global__ __launch_bounds__(256) void wpad_kernel(const float* __restrict__ w, float* __restrict__ wp) {
    int idx = blockIdx.x * 256 + threadIdx.x;
    wp[idx] = (idx < 56 * 256) ? w[idx] : 0.f;
}

__global__ __launch_bounds__(256) void cls_write(const float* __restrict__ tok, float* __restrict__ xd) {
    xd[(size_t)blockIdx.x * SEQ * WDIM + threadIdx.x] = tok[threadIdx.x];
}

// ---------------- LayerNorm (one row of 256 per block) ----------------
__global__ __launch_bounds__(256) void ln_kernel(const float* __restrict__ in, float* __restrict__ out,
                                                 const float* __restrict__ g, const float* __restrict__ be,
                                                 int rin_mul, int rout_mul) {
    int t = threadIdx.x;
    size_t ib = (size_t)blockIdx.x * rin_mul * WDIM;
    size_t ob = (size_t)blockIdx.x * rout_mul * WDIM;
    float v = in[ib + t];
    float s = v, ss = v * v;
#pragma unroll
    for (int off = 1; off < 64; off <<= 1) { s += __shfl_xor(s, off); ss += __shfl_xor(ss, off); }
    __shared__ float red[8];
    if ((t & 63) == 0) { red[t >> 6] = s; red[4 + (t >> 6)] = ss; }
    __syncthreads();
    s = red[0] + red[1] + red[2] + red[3];
    ss = red[4] + red[5] + red[6] + red[7];
    float mean = s * 0.00390625f;
    float var = ss * 0.00390625f - mean * mean;
    float rs = rsqrtf(var + 1e-5f);
    out[ob + t] = (v - mean) * rs * g[t] + be[t];
}

// ---------------- standard tiled fp32 GEMM: C = epi(A[M,K] @ B[K,N] + bias) ----------------
// BM=BN=64, BK=16, 256 threads, 4x4 per thread. All M,N,K exact multiples in our uses.
template <int ACT, bool RESID, bool REMAP>
__global__ __launch_bounds__(256) void gemm_std(const float* __restrict__ A, int lda,
                                                const float* __restrict__ Bw, int ldb,
                                                const float* __restrict__ bias,
                                                float* __restrict__ C, int ldc, int Ktot) {
    int t = threadIdx.x;
    int m0 = blockIdx.x << 6, n0 = blockIdx.y << 6;
    __shared__ float As[16][68];
    __shared__ float Bs[16][64];
    int arow = t >> 2, akk = (t & 3) << 2;
    int bk = t >> 4, bn = (t & 15) << 2;
    int tm = (t >> 4) << 2, tn = (t & 15) << 2;
    float acc[4][4] = {};
    const float* ap = A + (size_t)(m0 + arow) * lda + akk;
    const float* bp = Bw + (size_t)bk * ldb + n0 + bn;
    for (int k0 = 0; k0 < Ktot; k0 += 16) {
        float4 av = *(const float4*)(ap + k0);
        float4 bv = *(const float4*)(bp + (size_t)k0 * ldb);
        __syncthreads();
        As[akk + 0][arow] = av.x; As[akk + 1][arow] = av.y;
        As[akk + 2][arow] = av.z; As[akk + 3][arow] = av.w;
        *(float4*)&Bs[bk][bn] = bv;
        __syncthreads();
#pragma unroll
        for (int k = 0; k < 16; ++k) {
            float4 a = *(const float4*)&As[k][tm];
            float4 b = *(const float4*)&Bs[k][tn];
            acc[0][0] += a.x * b.x; acc[0][1] += a.x * b.y; acc[0][2] += a.x * b.z; acc[0][3] += a.x * b.w;
            acc[1][0] += a.y * b.x; acc[1][1] += a.y * b.y; acc[1][2] += a.y * b.z; acc[1][3] += a.y * b.w;
            acc[2][0] += a.z * b.x; acc[2][1] += a.z * b.y; acc[2][2] += a.z * b.z; acc[2][3] += a.z * b.w;
            acc[3][0] += a.w * b.x; acc[3][1] += a.w * b.y; acc[3][2] += a.w * b.z; acc[3][3] += a.w * b.w;
        }
    }
#pragma unroll
    for (int i = 0; i < 4; ++i) {
        int gm = m0 + tm + i;
        int orow = REMAP ? (gm + (gm >> 8) + 1) : gm;  // node -> xd row (skip cls slots)
        float* cp = C + (size_t)orow * ldc + n0 + tn;
        float4 r;
        r.x = acc[i][0] + bias[n0 + tn + 0];
        r.y = acc[i][1] + bias[n0 + tn + 1];
        r.z = acc[i][2] + bias[n0 + tn + 2];
        r.w = acc[i][3] + bias[n0 + tn + 3];
        if (ACT == 1) { r.x = gelu_f(r.x); r.y = gelu_f(r.y); r.z = gelu_f(r.z); r.w = gelu_f(r.w); }
        if (ACT == 2) { r.x = fmaxf(r.x, 0.f); r.y = fmaxf(r.y, 0.f); r.z = fmaxf(r.z, 0.f); r.w = fmaxf(r.w, 0.f); }
        if (RESID) {
            float4 o = *(const float4*)cp;
            r.x += o.x; r.y += o.y; r.z += o.z; r.w += o.w;
        }
        *(float4*)cp = r;
    }
}

// ---------------- attention: QK^T (batched, chunk of 16 graphs) ----------------
// grid (5 qt, 5 kt, 128 bh); S[bb][q][k] = scale * sum_d Q[q,d]*K[k,d]
__global__ __launch_bounds__(256) void qk_kernel(const float* __restrict__ qkvb, float* __restrict__ sc, int b0) {
    int t = threadIdx.x;
    int m0 = blockIdx.x << 6, n0 = blockIdx.y << 6;
    int bb = blockIdx.z;
    int b = b0 + (bb >> 3), h = bb & 7;
    __shared__ float As[32][68];
    __shared__ float Bs[32][64];
    const float* qbase = qkvb + (size_t)(b * SEQ) * 768 + h * 32;
    const float* kbase = qkvb + (size_t)(b * SEQ) * 768 + 256 + h * 32;
    {
        int arow = t >> 2, akk = (t & 3) << 2;
        int gq = m0 + arow;
        float4 a0 = {0, 0, 0, 0}, a1 = {0, 0, 0, 0};
        if (gq < SEQ) {
            const float* p = qbase + (size_t)gq * 768 + akk;
            a0 = *(const float4*)p;
            a1 = *(const float4*)(p + 16);
        }
        As[akk + 0][arow] = a0.x; As[akk + 1][arow] = a0.y; As[akk + 2][arow] = a0.z; As[akk + 3][arow] = a0.w;
        As[16 + akk + 0][arow] = a1.x; As[16 + akk + 1][arow] = a1.y;
        As[16 + akk + 2][arow] = a1.z; As[16 + akk + 3][arow] = a1.w;
    }
    {
        int kk = t & 63, d4 = (t >> 6) << 2;
        int gk = n0 + kk;
        float4 v0 = {0, 0, 0, 0}, v1 = {0, 0, 0, 0};
        if (gk < SEQ) {
            const float* p = kbase + (size_t)gk * 768 + d4;
            v0 = *(const float4*)p;
            v1 = *(const float4*)(p + 16);
        }
        Bs[d4 + 0][kk] = v0.x; Bs[d4 + 1][kk] = v0.y; Bs[d4 + 2][kk] = v0.z; Bs[d4 + 3][kk] = v0.w;
        Bs[16 + d4 + 0][kk] = v1.x; Bs[16 + d4 + 1][kk] = v1.y;
        Bs[16 + d4 + 2][kk] = v1.z; Bs[16 + d4 + 3][kk] = v1.w;
    }
    __syncthreads();
    int tm = (t >> 4) << 2, tn = (t & 15) << 2;
    float acc[4][4] = {};
#pragma unroll
    for (int k = 0; k < 32; ++k) {
        float4 a = *(const float4*)&As[k][tm];
        float4 b = *(const float4*)&Bs[k][tn];
        acc[0][0] += a.x * b.x; acc[0][1] += a.x * b.y; acc[0][2] += a.x * b.z; acc[0][3] += a.x * b.w;
        acc[1][0] += a.y * b.x; acc[1][1] += a.y * b.y; acc[1][2] += a.y * b.z; acc[1][3] += a.y * b.w;
        acc[2][0] += a.z * b.x; acc[2][1] += a.z * b.y; acc[2][2] += a.z * b.z; acc[2][3] += a.z * b.w;
        acc[3][0] += a.w * b.x; acc[3][1] += a.w * b.y; acc[3][2] += a.w * b.z; acc[3][3] += a.w * b.w;
    }
    const float scale = 0.17677669529663687f;  // 1/sqrt(32)
    float* out = sc + (size_t)bb * SEQ * SEQ;
#pragma unroll
    for (int i = 0; i < 4; ++i) {
        int q = m0 + tm + i;
        if (q >= SEQ) continue;
#pragma unroll
        for (int j = 0; j < 4; ++j) {
            int kk = n0 + tn + j;
            if (kk < SEQ) out[(size_t)q * SEQ + kk] = acc[i][j] * scale;
        }
    }
}

// masked softmax over one score row (wave per row); mask: q==0 -> all, else k<=q
__global__ __launch_bounds__(256) void softmax_kernel(float* __restrict__ sc) {
    int r = blockIdx.x * 4 + (threadIdx.x >> 6);
    int lane = threadIdx.x & 63;
    int bb = r / SEQ, q = r - bb * SEQ;
    float* base = sc + ((size_t)bb * SEQ + q) * SEQ;
    float xv[5];
    float m = -3.0e38f;
#pragma unroll
    for (int j = 0; j < 5; ++j) {
        int k = lane + (j << 6);
        bool ok = (k < SEQ) && (q == 0 || k <= q);
        xv[j] = ok ? base[k] : -1.0e30f;
        m = fmaxf(m, xv[j]);
    }
#pragma unroll
    for (int off = 1; off < 64; off <<= 1) m = fmaxf(m, __shfl_xor(m, off));
    float s = 0.f;
#pragma unroll
    for (int j = 0; j < 5; ++j) { xv[j] = expf(xv[j] - m); s += xv[j]; }
#pragma unroll
    for (int off = 1; off < 64; off <<= 1) s += __shfl_xor(s, off);
    float inv = 1.0f / s;
#pragma unroll
    for (int j = 0; j < 5; ++j) {
        int k = lane + (j << 6);
        if (k < SEQ) base[k] = xv[j] * inv;
    }
}

// O = P @ V  (M=257 tiled by 64, N=32, K=257); writes into Q slice of qkv (dead by now)
__global__ __launch_bounds__(256) void pv_kernel(const float* __restrict__ sc, float* __restrict__ qkvb, int b0) {
    int t = threadIdx.x;
    int m0 = blockIdx.x << 6;
    int bb = blockIdx.y;
    int b = b0 + (bb >> 3), h = bb & 7;
    const float* P = sc + (size_t)bb * SEQ * SEQ;
    const float* vbase = qkvb + (size_t)(b * SEQ) * 768 + 512 + h * 32;
    float* obase = qkvb + (size_t)(b * SEQ) * 768 + h * 32;
    __shared__ float As[16][68];
    __shared__ float Vs[16][32];
    int arow = t >> 2, akk = (t & 3) << 2;
    int vk = t >> 4, vd = (t & 15) << 1;
    int tm = (t >> 4) << 2, tn = (t & 15) << 1;
    float acc[4][2] = {};
    for (int k0 = 0; k0 < SEQ; k0 += 16) {
        int gq = m0 + arow;
        float a[4];
#pragma unroll
        for (int j = 0; j < 4; ++j) {
            int gk = k0 + akk + j;
            a[j] = (gq < SEQ && gk < SEQ) ? P[(size_t)gq * SEQ + gk] : 0.f;
        }
        int gvk = k0 + vk;
        float2 vv = {0, 0};
        if (gvk < SEQ) vv = *(const float2*)(vbase + (size_t)gvk * 768 + vd);
        __syncthreads();
        As[akk + 0][arow] = a[0]; As[akk + 1][arow] = a[1];
        As[akk + 2][arow] = a[2]; As[akk + 3][arow] = a[3];
        *(float2*)&Vs[vk][vd] = vv;
        __syncthreads();
#pragma unroll
        for (int k = 0; k < 16; ++k) {
            float4 av = *(const float4*)&As[k][tm];
            float2 bv = *(const float2*)&Vs[k][tn];
            acc[0][0] += av.x * bv.x; acc[0][1] += av.x * bv.y;
            acc[1][0] += av.y * bv.x; acc[1][1] += av.y * bv.y;
            acc[2][0] += av.z * bv.x; acc[2][1] += av.z * bv.y;
            acc[3][0] += av.w * bv.x; acc[3][1] += av.w * bv.y;
        }
    }
#pragma unroll
    for (int i = 0; i < 4; ++i) {
        int q = m0 + tm + i;
        if (q < SEQ) {
            float2 r; r.x = acc[i][0]; r.y = acc[i][1];
            *(float2*)(obase + (size_t)q * 768 + tn) = r;
        }
    }
}

// ---------------- decoder: one sample row per block ----------------
__global__ __launch_bounds__(256) void dec_fc(const float* __restrict__ in, const float* __restrict__ w,
                                              const float* __restrict__ bia, float* __restrict__ out,
                                              int K, int Nout) {
    __shared__ float rowbuf[512];
    int b = blockIdx.x, t = threadIdx.x;
    for (int i = t; i < K; i += 256) rowbuf[i] = in[(size_t)b * K + i];
    __syncthreads();
    for (int n = t; n < Nout; n += 256) {
        float s = bia[n];
        for (int k = 0; k < K; ++k) s += rowbuf[k] * w[(size_t)k * Nout + n];
        out[(size_t)b * Nout + n] = fmaxf(s, 0.f);
    }
}

// ---------------- launch ----------------
extern "C" void kernel_launch(void* const* d_in, const int* in_sizes, int n_in,
                              void* d_out, int out_size, void* d_ws, size_t ws_size,
                              hipStream_t stream) {
    const float* x         = (const float*)d_in[0];
    const float* p         = (const float*)d_in[1];
    const int*   ei        = (const int*)d_in[2];
    const float* gcn_w     = (const float*)d_in[4];
    const float* gcn_b     = (const float*)d_in[5];
    const float* cls_tok   = (const float*)d_in[6];
    const float* ln_pre_s  = (const float*)d_in[7];
    const float* ln_pre_b  = (const float*)d_in[8];
    const float* norm1_s   = (const float*)d_in[9];
    const float* norm1_b   = (const float*)d_in[10];
    const float* in_proj_w = (const float*)d_in[11];
    const float* in_proj_b = (const float*)d_in[12];
    const float* out_proj_w= (const float*)d_in[13];
    const float* out_proj_b= (const float*)d_in[14];
    const float* norm2_s   = (const float*)d_in[15];
    const float* norm2_b   = (const float*)d_in[16];
    const float* ff_w1     = (const float*)d_in[17];
    const float* ff_b1     = (const float*)d_in[18];
    const float* ff_w2     = (const float*)d_in[19];
    const float* ff_b2     = (const float*)d_in[20];
    const float* ln_post_s = (const float*)d_in[21];
    const float* ln_post_b = (const float*)d_in[22];
    const float* dec_w1    = (const float*)d_in[23];
    const float* dec_b1    = (const float*)d_in[24];
    const float* dec_w2    = (const float*)d_in[25];
    const float* dec_b2    = (const float*)d_in[26];
    const float* dec_w3    = (const float*)d_in[27];
    const float* dec_b3    = (const float*)d_in[28];

    float* ws   = (float*)d_ws;
    float* y    = ws + F_Y;
    float* agg  = ws + F_AGG;
    float* xd   = ws + F_XD;
    float* h1   = ws + F_H1;
    float* qkv  = ws + F_QKV;
    float* ffb  = ws + F_FFB;
    float* sc   = ffb;  // alias: scores live only while ffb is dead
    float* cls  = ws + F_CLS;
    float* dd1  = ws + F_D1;
    float* dd2  = ws + F_D2;
    float* wpad = ws + F_WPAD;
    float* dinv = ws + F_DINV;
    int* ibase  = (int*)(ws + F_END);
    int* indeg  = ibase;
    int* offs   = ibase + N_NODES;
    int* cursor = offs + N_NODES + 1;
    int* csr    = cursor + N_NODES;

    // GCN prelude
    hipMemsetAsync(indeg, 0, N_NODES * sizeof(int), stream);
    hist_kernel<<<NEDGE / 256, 256, 0, stream>>>(ei + NEDGE, indeg);
    scan_kernel<<<1, 1024, 0, stream>>>(indeg, offs, cursor, dinv);
    fill_kernel<<<NEDGE / 256, 256, 0, stream>>>(ei, cursor, csr);
    y_kernel<<<N_NODES * 64 / 256, 256, 0, stream>>>(x, p, dinv, y);
    agg_kernel<<<N_NODES / 4, 256, 0, stream>>>(y, dinv, offs, csr, agg);
    wpad_kernel<<<64, 256, 0, stream>>>(gcn_w, wpad);
    // GCN matmul -> xd rows (remapped past cls slots)
    gemm_std<0, false, true><<<dim3(256, 4), 256, 0, stream>>>(agg, 64, wpad, 256, gcn_b, xd, 256, 64);
    cls_write<<<64, 256, 0, stream>>>(cls_tok, xd);
    ln_kernel<<<MROWS, 256, 0, stream>>>(xd, xd, ln_pre_s, ln_pre_b, 1, 1);

    for (int l = 0; l < 2; ++l) {
        ln_kernel<<<MROWS, 256, 0, stream>>>(xd, h1, norm1_s + l * WDIM, norm1_b + l * WDIM, 1, 1);
        gemm_std<0, false, false><<<dim3(257, 12), 256, 0, stream>>>(
            h1, 256, in_proj_w + (size_t)l * WDIM * 3 * WDIM, 768, in_proj_b + l * 768, qkv, 768, 256);
        for (int c = 0; c < 4; ++c) {
            int b0 = c * 16;
            qk_kernel<<<dim3(5, 5, 128), 256, 0, stream>>>(qkv, sc, b0);
            softmax_kernel<<<(128 * SEQ) / 4, 256, 0, stream>>>(sc);
            pv_kernel<<<dim3(5, 128), 256, 0, stream>>>(sc, qkv, b0);
        }
        gemm_std<0, true, false><<<dim3(257, 4), 256, 0, stream>>>(
            qkv, 768, out_proj_w + (size_t)l * WDIM * WDIM, 256, out_proj_b + l * WDIM, xd, 256, 256);
        ln_kernel<<<MROWS, 256, 0, stream>>>(xd, h1, norm2_s + l * WDIM, norm2_b + l * WDIM, 1, 1);
        gemm_std<1, false, false><<<dim3(257, 16), 256, 0, stream>>>(
            h1, 256, ff_w1 + (size_t)l * WDIM * DFF, 1024, ff_b1 + l * DFF, ffb, 1024, 256);
        gemm_std<1, true, false><<<dim3(257, 4), 256, 0, stream>>>(
            ffb, 1024, ff_w2 + (size_t)l * DFF * WDIM, 256, ff_b2 + l * WDIM, xd, 256, 1024);
    }

    // cls extract + ln_post + decoder
    ln_kernel<<<BGRAPH, 256, 0, stream>>>(xd, cls, ln_post_s, ln_post_b, SEQ, 1);
    dec_fc<<<BGRAPH, 256, 0, stream>>>(cls, dec_w1, dec_b1, dd1, 256, 512);
    dec_fc<<<BGRAPH, 256, 0, stream>>>(dd1, dec_w2, dec_b2, dd2, 512, 512);
    dec_fc<<<BGRAPH, 256, 0, stream>>>(dd2, dec_w3, dec_b3, (float*)d_out, 512, 64);
}

// Round 2
// 1504.538 us; speedup vs baseline: 1.3257x; 1.3257x over previous
//
#include <hip/hip_runtime.h>
#include <math.h>

// ---------------- model dims ----------------
constexpr int N_NODES = 16384;
constexpr int BGRAPH  = 64;
constexpr int NEDGE   = 524288;
constexpr int SEQ     = 257;           // NPG + cls
constexpr int WDIM    = 256;
constexpr int DFF     = 1024;
constexpr int HID     = 512;
constexpr int MROWS   = BGRAPH * SEQ;  // 16448

// ---------------- ws layout (float offsets) ----------------
constexpr size_t F_Y    = 0;                                   // [N,64] dinv-scaled padded xc
constexpr size_t F_AGG  = F_Y    + (size_t)N_NODES * 64;       // [N,64]
constexpr size_t F_XD   = F_AGG  + (size_t)N_NODES * 64;       // [16448,256] residual stream
constexpr size_t F_H1   = F_XD   + (size_t)MROWS * WDIM;       // [16448,256] post-LN
constexpr size_t F_QKV  = F_H1   + (size_t)MROWS * WDIM;       // [16448,768]
constexpr size_t F_FFB  = F_QKV  + (size_t)MROWS * 3 * WDIM;   // [16448,1024]; scores alias here
constexpr size_t F_CLS  = F_FFB  + (size_t)MROWS * DFF;        // [64,256]
constexpr size_t F_D1   = F_CLS  + (size_t)BGRAPH * WDIM;      // [64,512]
constexpr size_t F_D2   = F_D1   + (size_t)BGRAPH * HID;       // [64,512]
constexpr size_t F_WPAD = F_D2   + (size_t)BGRAPH * HID;       // [64,256] zero-padded gcn_w
constexpr size_t F_DINV = F_WPAD + (size_t)64 * WDIM;          // [N]
constexpr size_t F_END  = F_DINV + (size_t)N_NODES;

typedef __attribute__((ext_vector_type(8))) __bf16 bf16x8;
typedef __attribute__((ext_vector_type(4))) float f32x4;

__device__ __forceinline__ float gelu_f(float x) {
    float u = 0.7978845608028654f * (x + 0.044715f * x * x * x);
    return 0.5f * x * (1.0f + tanhf(u));
}

// ---------------- GCN prelude ----------------
__global__ __launch_bounds__(256) void hist_kernel(const int* __restrict__ col, int* __restrict__ indeg) {
    int e = blockIdx.x * 256 + threadIdx.x;
    atomicAdd(&indeg[col[e]], 1);
}

__global__ __launch_bounds__(1024) void scan_kernel(const int* __restrict__ indeg, int* __restrict__ offs,
                                                    int* __restrict__ cursor, float* __restrict__ dinv) {
    __shared__ int parts[1024];
    int t = threadIdx.x;
    int base = t * 16;
    int loc[16];
    int s = 0;
#pragma unroll
    for (int i = 0; i < 16; ++i) { loc[i] = indeg[base + i]; s += loc[i]; }
    parts[t] = s;
    __syncthreads();
    for (int off = 1; off < 1024; off <<= 1) {
        int v = (t >= off) ? parts[t - off] : 0;
        __syncthreads();
        parts[t] += v;
        __syncthreads();
    }
    int run = (t == 0) ? 0 : parts[t - 1];
#pragma unroll
    for (int i = 0; i < 16; ++i) {
        offs[base + i] = run;
        cursor[base + i] = run;
        dinv[base + i] = rsqrtf((float)loc[i] + 1.0f);  // deg = indeg + self-loop
        run += loc[i];
    }
    if (t == 1023) offs[N_NODES] = run;
}

__global__ __launch_bounds__(256) void fill_kernel(const int* __restrict__ ei, int* __restrict__ cursor,
                                                   int* __restrict__ csr) {
    int e = blockIdx.x * 256 + threadIdx.x;
    int r = ei[e];            // source
    int c = ei[NEDGE + e];    // destination
    int pos = atomicAdd(&cursor[c], 1);
    csr[pos] = r;
}

// xc = [x(32) | sin(p*2^j*pi)(24) | 0(8)], pre-scaled by dinv[node]
__global__ __launch_bounds__(256) void y_kernel(const float* __restrict__ x, const float* __restrict__ p,
                                                const float* __restrict__ dinv, float* __restrict__ y) {
    int idx = blockIdx.x * 256 + threadIdx.x;
    int i = idx >> 6, d = idx & 63;
    float v = 0.f;
    if (d < 32) {
        v = x[i * 32 + d];
    } else if (d < 56) {
        int dd = d - 32;
        int dim = dd >> 3, j = dd & 7;
        v = sinf(p[i * 3 + dim] * (3.14159265358979323846f * (float)(1 << j)));
    }
    y[idx] = dinv[i] * v;
}

// agg[c] = dinv[c] * (y[c] + sum_{in-edges} y[src])   (wave per node)
__global__ __launch_bounds__(256) void agg_kernel(const float* __restrict__ y, const float* __restrict__ dinv,
                                                  const int* __restrict__ offs, const int* __restrict__ csr,
                                                  float* __restrict__ agg) {
    int c = (blockIdx.x * 256 + threadIdx.x) >> 6;
    int lane = threadIdx.x & 63;
    float acc = y[(size_t)c * 64 + lane];
    int s = offs[c], e = offs[c + 1];
    for (int j = s; j < e; ++j) {
        int r = csr[j];
        acc += y[(size_t)r * 64 + lane];
    }
    agg[(size_t)c * 64 + lane] = dinv[c] * acc;
}

__global__ __launch_bounds__(256) void wpad_kernel(const float* __restrict__ w, float* __restrict__ wp) {
    int idx = blockIdx.x * 256 + threadIdx.x;
    wp[idx] = (idx < 56 * 256) ? w[idx] : 0.f;
}

__global__ __launch_bounds__(256) void cls_write(const float* __restrict__ tok, float* __restrict__ xd) {
    xd[(size_t)blockIdx.x * SEQ * WDIM + threadIdx.x] = tok[threadIdx.x];
}

// ---------------- LayerNorm (one row of 256 per block) ----------------
__global__ __launch_bounds__(256) void ln_kernel(const float* __restrict__ in, float* __restrict__ out,
                                                 const float* __restrict__ g, const float* __restrict__ be,
                                                 int rin_mul, int rout_mul) {
    int t = threadIdx.x;
    size_t ib = (size_t)blockIdx.x * rin_mul * WDIM;
    size_t ob = (size_t)blockIdx.x * rout_mul * WDIM;
    float v = in[ib + t];
    float s = v, ss = v * v;
#pragma unroll
    for (int off = 1; off < 64; off <<= 1) { s += __shfl_xor(s, off); ss += __shfl_xor(ss, off); }
    __shared__ float red[8];
    if ((t & 63) == 0) { red[t >> 6] = s; red[4 + (t >> 6)] = ss; }
    __syncthreads();
    s = red[0] + red[1] + red[2] + red[3];
    ss = red[4] + red[5] + red[6] + red[7];
    float mean = s * 0.00390625f;
    float var = ss * 0.00390625f - mean * mean;
    float rs = rsqrtf(var + 1e-5f);
    out[ob + t] = (v - mean) * rs * g[t] + be[t];
}

// ---------------- weight transpose+cast: W[K][N] fp32 -> Wt[N][K] bf16 ----------------
__global__ __launch_bounds__(256) void tcast_kernel(const float* __restrict__ W, __bf16* __restrict__ Wt,
                                                    int K, int N) {
    __shared__ __bf16 T[64][65];
    int t = threadIdx.x;
    int k0 = blockIdx.x << 6, n0 = blockIdx.y << 6;
#pragma unroll
    for (int i = 0; i < 16; ++i) {
        int idx = t + i * 256;
        int k = idx >> 6, n = idx & 63;
        T[k][n] = (__bf16)W[(size_t)(k0 + k) * N + n0 + n];
    }
    __syncthreads();
#pragma unroll
    for (int i = 0; i < 16; ++i) {
        int idx = t + i * 256;
        int n = idx >> 6, k = idx & 63;
        Wt[(size_t)(n0 + n) * K + k0 + k] = T[k][n];
    }
}

// ---------------- bf16 MFMA GEMM: C[M,N] = epi(A[M,K](fp32) @ Bt[N,K](bf16) + bias) ----------------
// 128x128 tile, BK=32, 256 threads = 4 waves, each wave 64x64 (4x4 mfma tiles of 16x16x32).
// M may have a partial last tile (guarded stores; A overflow reads stay inside ws).
template <int ACT, bool RESID>
__global__ __launch_bounds__(256) void gemm_mfma(const float* __restrict__ A, int lda,
                                                 const __bf16* __restrict__ Bt,
                                                 const float* __restrict__ bias,
                                                 float* __restrict__ C, int ldc,
                                                 int Ktot, int Mrows) {
    __shared__ __bf16 As[128 * 32];
    __shared__ __bf16 Bs[128 * 32];
    int t = threadIdx.x;
    int m0 = blockIdx.x << 7, n0 = blockIdx.y << 7;
    int w = t >> 6, L = t & 63;
    int wm = w >> 1, wn = w & 1;

    // staging: thread t handles one row-half (16 elements of k)
    int srow = t >> 1, skc = (t & 1) << 4;
    const float* ap = A + (size_t)(m0 + srow) * lda + skc;
    const __bf16* bp = Bt + (size_t)(n0 + srow) * Ktot + skc;

    // fragment read offsets (bf16 element index)
    int lc = L & 15, lq = L >> 4;
    int a_base = (wm * 64 + lc) * 32 + lq * 8;
    int b_base = (wn * 64 + lc) * 32 + lq * 8;

    f32x4 acc[4][4] = {};

    for (int k0 = 0; k0 < Ktot; k0 += 32) {
        // global loads
        f32x4 a0 = *(const f32x4*)(ap + k0);
        f32x4 a1 = *(const f32x4*)(ap + k0 + 4);
        f32x4 a2 = *(const f32x4*)(ap + k0 + 8);
        f32x4 a3 = *(const f32x4*)(ap + k0 + 12);
        f32x4 b0 = *(const f32x4*)(bp + k0);       // 8 bf16
        f32x4 b1 = *(const f32x4*)(bp + k0 + 8);   // 8 bf16
        __syncthreads();
        // convert A -> bf16, store LDS
        bf16x8 pa0, pa1;
        pa0[0] = (__bf16)a0.x; pa0[1] = (__bf16)a0.y; pa0[2] = (__bf16)a0.z; pa0[3] = (__bf16)a0.w;
        pa0[4] = (__bf16)a1.x; pa0[5] = (__bf16)a1.y; pa0[6] = (__bf16)a1.z; pa0[7] = (__bf16)a1.w;
        pa1[0] = (__bf16)a2.x; pa1[1] = (__bf16)a2.y; pa1[2] = (__bf16)a2.z; pa1[3] = (__bf16)a2.w;
        pa1[4] = (__bf16)a3.x; pa1[5] = (__bf16)a3.y; pa1[6] = (__bf16)a3.z; pa1[7] = (__bf16)a3.w;
        *(bf16x8*)&As[srow * 32 + skc]     = pa0;
        *(bf16x8*)&As[srow * 32 + skc + 8] = pa1;
        *(f32x4*)&Bs[srow * 32 + skc]     = b0;
        *(f32x4*)&Bs[srow * 32 + skc + 8] = b1;
        __syncthreads();
        // fragments + MFMA
        bf16x8 af[4], bf[4];
#pragma unroll
        for (int i = 0; i < 4; ++i) {
            af[i] = *(const bf16x8*)&As[a_base + i * 512];
            bf[i] = *(const bf16x8*)&Bs[b_base + i * 512];
        }
#pragma unroll
        for (int mt = 0; mt < 4; ++mt)
#pragma unroll
            for (int nt = 0; nt < 4; ++nt)
                acc[mt][nt] = __builtin_amdgcn_mfma_f32_16x16x32_bf16(af[mt], bf[nt], acc[mt][nt], 0, 0, 0);
    }

    // epilogue: lane L holds rows lq*4+0..3, col lc of each 16x16 tile
#pragma unroll
    for (int mt = 0; mt < 4; ++mt) {
        int gm_base = m0 + wm * 64 + mt * 16 + lq * 4;
#pragma unroll
        for (int nt = 0; nt < 4; ++nt) {
            int gn = n0 + wn * 64 + nt * 16 + lc;
            float bv = bias[gn];
#pragma unroll
            for (int r = 0; r < 4; ++r) {
                int gm = gm_base + r;
                if (gm >= Mrows) continue;
                float v = acc[mt][nt][r] + bv;
                if (ACT == 1) v = gelu_f(v);
                float* cp = C + (size_t)gm * ldc + gn;
                if (RESID) v += *cp;
                *cp = v;
            }
        }
    }
}

// ---------------- attention: QK^T (batched, chunk of 16 graphs) ----------------
__global__ __launch_bounds__(256) void qk_kernel(const float* __restrict__ qkvb, float* __restrict__ sc, int b0) {
    int t = threadIdx.x;
    int m0 = blockIdx.x << 6, n0 = blockIdx.y << 6;
    int bb = blockIdx.z;
    int b = b0 + (bb >> 3), h = bb & 7;
    __shared__ float As[32][68];
    __shared__ float Bs[32][64];
    const float* qbase = qkvb + (size_t)(b * SEQ) * 768 + h * 32;
    const float* kbase = qkvb + (size_t)(b * SEQ) * 768 + 256 + h * 32;
    {
        int arow = t >> 2, akk = (t & 3) << 2;
        int gq = m0 + arow;
        float4 a0 = {0, 0, 0, 0}, a1 = {0, 0, 0, 0};
        if (gq < SEQ) {
            const float* p = qbase + (size_t)gq * 768 + akk;
            a0 = *(const float4*)p;
            a1 = *(const float4*)(p + 16);
        }
        As[akk + 0][arow] = a0.x; As[akk + 1][arow] = a0.y; As[akk + 2][arow] = a0.z; As[akk + 3][arow] = a0.w;
        As[16 + akk + 0][arow] = a1.x; As[16 + akk + 1][arow] = a1.y;
        As[16 + akk + 2][arow] = a1.z; As[16 + akk + 3][arow] = a1.w;
    }
    {
        int kk = t & 63, d4 = (t >> 6) << 2;
        int gk = n0 + kk;
        float4 v0 = {0, 0, 0, 0}, v1 = {0, 0, 0, 0};
        if (gk < SEQ) {
            const float* p = kbase + (size_t)gk * 768 + d4;
            v0 = *(const float4*)p;
            v1 = *(const float4*)(p + 16);
        }
        Bs[d4 + 0][kk] = v0.x; Bs[d4 + 1][kk] = v0.y; Bs[d4 + 2][kk] = v0.z; Bs[d4 + 3][kk] = v0.w;
        Bs[16 + d4 + 0][kk] = v1.x; Bs[16 + d4 + 1][kk] = v1.y;
        Bs[16 + d4 + 2][kk] = v1.z; Bs[16 + d4 + 3][kk] = v1.w;
    }
    __syncthreads();
    int tm = (t >> 4) << 2, tn = (t & 15) << 2;
    float acc[4][4] = {};
#pragma unroll
    for (int k = 0; k < 32; ++k) {
        float4 a = *(const float4*)&As[k][tm];
        float4 b = *(const float4*)&Bs[k][tn];
        acc[0][0] += a.x * b.x; acc[0][1] += a.x * b.y; acc[0][2] += a.x * b.z; acc[0][3] += a.x * b.w;
        acc[1][0] += a.y * b.x; acc[1][1] += a.y * b.y; acc[1][2] += a.y * b.z; acc[1][3] += a.y * b.w;
        acc[2][0] += a.z * b.x; acc[2][1] += a.z * b.y; acc[2][2] += a.z * b.z; acc[2][3] += a.z * b.w;
        acc[3][0] += a.w * b.x; acc[3][1] += a.w * b.y; acc[3][2] += a.w * b.z; acc[3][3] += a.w * b.w;
    }
    const float scale = 0.17677669529663687f;  // 1/sqrt(32)
    float* out = sc + (size_t)bb * SEQ * SEQ;
#pragma unroll
    for (int i = 0; i < 4; ++i) {
        int q = m0 + tm + i;
        if (q >= SEQ) continue;
#pragma unroll
        for (int j = 0; j < 4; ++j) {
            int kk = n0 + tn + j;
            if (kk < SEQ) out[(size_t)q * SEQ + kk] = acc[i][j] * scale;
        }
    }
}

// masked softmax over one score row (wave per row); mask: q==0 -> all, else k<=q
__global__ __launch_bounds__(256) void softmax_kernel(float* __restrict__ sc) {
    int r = blockIdx.x * 4 + (threadIdx.x >> 6);
    int lane = threadIdx.x & 63;
    int bb = r / SEQ, q = r - bb * SEQ;
    float* base = sc + ((size_t)bb * SEQ + q) * SEQ;
    float xv[5];
    float m = -3.0e38f;
#pragma unroll
    for (int j = 0; j < 5; ++j) {
        int k = lane + (j << 6);
        bool ok = (k < SEQ) && (q == 0 || k <= q);
        xv[j] = ok ? base[k] : -1.0e30f;
        m = fmaxf(m, xv[j]);
    }
#pragma unroll
    for (int off = 1; off < 64; off <<= 1) m = fmaxf(m, __shfl_xor(m, off));
    float s = 0.f;
#pragma unroll
    for (int j = 0; j < 5; ++j) { xv[j] = expf(xv[j] - m); s += xv[j]; }
#pragma unroll
    for (int off = 1; off < 64; off <<= 1) s += __shfl_xor(s, off);
    float inv = 1.0f / s;
#pragma unroll
    for (int j = 0; j < 5; ++j) {
        int k = lane + (j << 6);
        if (k < SEQ) base[k] = xv[j] * inv;
    }
}

// O = P @ V  (M=257 tiled by 64, N=32, K=257); writes into Q slice of qkv (dead by now)
__global__ __launch_bounds__(256) void pv_kernel(const float* __restrict__ sc, float* __restrict__ qkvb, int b0) {
    int t = threadIdx.x;
    int m0 = blockIdx.x << 6;
    int bb = blockIdx.y;
    int b = b0 + (bb >> 3), h = bb & 7;
    const float* P = sc + (size_t)bb * SEQ * SEQ;
    const float* vbase = qkvb + (size_t)(b * SEQ) * 768 + 512 + h * 32;
    float* obase = qkvb + (size_t)(b * SEQ) * 768 + h * 32;
    __shared__ float As[16][68];
    __shared__ float Vs[16][32];
    int arow = t >> 2, akk = (t & 3) << 2;
    int vk = t >> 4, vd = (t & 15) << 1;
    int tm = (t >> 4) << 2, tn = (t & 15) << 1;
    float acc[4][2] = {};
    for (int k0 = 0; k0 < SEQ; k0 += 16) {
        int gq = m0 + arow;
        float a[4];
#pragma unroll
        for (int j = 0; j < 4; ++j) {
            int gk = k0 + akk + j;
            a[j] = (gq < SEQ && gk < SEQ) ? P[(size_t)gq * SEQ + gk] : 0.f;
        }
        int gvk = k0 + vk;
        float2 vv = {0, 0};
        if (gvk < SEQ) vv = *(const float2*)(vbase + (size_t)gvk * 768 + vd);
        __syncthreads();
        As[akk + 0][arow] = a[0]; As[akk + 1][arow] = a[1];
        As[akk + 2][arow] = a[2]; As[akk + 3][arow] = a[3];
        *(float2*)&Vs[vk][vd] = vv;
        __syncthreads();
#pragma unroll
        for (int k = 0; k < 16; ++k) {
            float4 av = *(const float4*)&As[k][tm];
            float2 bv = *(const float2*)&Vs[k][tn];
            acc[0][0] += av.x * bv.x; acc[0][1] += av.x * bv.y;
            acc[1][0] += av.y * bv.x; acc[1][1] += av.y * bv.y;
            acc[2][0] += av.z * bv.x; acc[2][1] += av.z * bv.y;
            acc[3][0] += av.w * bv.x; acc[3][1] += av.w * bv.y;
        }
    }
#pragma unroll
    for (int i = 0; i < 4; ++i) {
        int q = m0 + tm + i;
        if (q < SEQ) {
            float2 r; r.x = acc[i][0]; r.y = acc[i][1];
            *(float2*)(obase + (size_t)q * 768 + tn) = r;
        }
    }
}

// ---------------- fp32 tiled GEMM (kept for GCN projection) ----------------
template <int ACT, bool RESID, bool REMAP>
__global__ __launch_bounds__(256) void gemm_std(const float* __restrict__ A, int lda,
                                                const float* __restrict__ Bw, int ldb,
                                                const float* __restrict__ bias,
                                                float* __restrict__ C, int ldc, int Ktot) {
    int t = threadIdx.x;
    int m0 = blockIdx.x << 6, n0 = blockIdx.y << 6;
    __shared__ float As[16][68];
    __shared__ float Bs[16][64];
    int arow = t >> 2, akk = (t & 3) << 2;
    int bk = t >> 4, bn = (t & 15) << 2;
    int tm = (t >> 4) << 2, tn = (t & 15) << 2;
    float acc[4][4] = {};
    const float* ap = A + (size_t)(m0 + arow) * lda + akk;
    const float* bp = Bw + (size_t)bk * ldb + n0 + bn;
    for (int k0 = 0; k0 < Ktot; k0 += 16) {
        float4 av = *(const float4*)(ap + k0);
        float4 bv = *(const float4*)(bp + (size_t)k0 * ldb);
        __syncthreads();
        As[akk + 0][arow] = av.x; As[akk + 1][arow] = av.y;
        As[akk + 2][arow] = av.z; As[akk + 3][arow] = av.w;
        *(float4*)&Bs[bk][bn] = bv;
        __syncthreads();
#pragma unroll
        for (int k = 0; k < 16; ++k) {
            float4 a = *(const float4*)&As[k][tm];
            float4 b = *(const float4*)&Bs[k][tn];
            acc[0][0] += a.x * b.x; acc[0][1] += a.x * b.y; acc[0][2] += a.x * b.z; acc[0][3] += a.x * b.w;
            acc[1][0] += a.y * b.x; acc[1][1] += a.y * b.y; acc[1][2] += a.y * b.z; acc[1][3] += a.y * b.w;
            acc[2][0] += a.z * b.x; acc[2][1] += a.z * b.y; acc[2][2] += a.z * b.z; acc[2][3] += a.z * b.w;
            acc[3][0] += a.w * b.x; acc[3][1] += a.w * b.y; acc[3][2] += a.w * b.z; acc[3][3] += a.w * b.w;
        }
    }
#pragma unroll
    for (int i = 0; i < 4; ++i) {
        int gm = m0 + tm + i;
        int orow = REMAP ? (gm + (gm >> 8) + 1) : gm;  // node -> xd row (skip cls slots)
        float* cp = C + (size_t)orow * ldc + n0 + tn;
        float4 r;
        r.x = acc[i][0] + bias[n0 + tn + 0];
        r.y = acc[i][1] + bias[n0 + tn + 1];
        r.z = acc[i][2] + bias[n0 + tn + 2];
        r.w = acc[i][3] + bias[n0 + tn + 3];
        if (ACT == 1) { r.x = gelu_f(r.x); r.y = gelu_f(r.y); r.z = gelu_f(r.z); r.w = gelu_f(r.w); }
        if (ACT == 2) { r.x = fmaxf(r.x, 0.f); r.y = fmaxf(r.y, 0.f); r.z = fmaxf(r.z, 0.f); r.w = fmaxf(r.w, 0.f); }
        if (RESID) {
            float4 o = *(const float4*)cp;
            r.x += o.x; r.y += o.y; r.z += o.z; r.w += o.w;
        }
        *(float4*)cp = r;
    }
}

// ---------------- decoder: one sample row per block ----------------
__global__ __launch_bounds__(256) void dec_fc(const float* __restrict__ in, const float* __restrict__ w,
                                              const float* __restrict__ bia, float* __restrict__ out,
                                              int K, int Nout) {
    __shared__ float rowbuf[512];
    int b = blockIdx.x, t = threadIdx.x;
    for (int i = t; i < K; i += 256) rowbuf[i] = in[(size_t)b * K + i];
    __syncthreads();
    for (int n = t; n < Nout; n += 256) {
        float s = bia[n];
        for (int k = 0; k < K; ++k) s += rowbuf[k] * w[(size_t)k * Nout + n];
        out[(size_t)b * Nout + n] = fmaxf(s, 0.f);
    }
}

// ---------------- launch ----------------
extern "C" void kernel_launch(void* const* d_in, const int* in_sizes, int n_in,
                              void* d_out, int out_size, void* d_ws, size_t ws_size,
                              hipStream_t stream) {
    const float* x         = (const float*)d_in[0];
    const float* p         = (const float*)d_in[1];
    const int*   ei        = (const int*)d_in[2];
    const float* gcn_w     = (const float*)d_in[4];
    const float* gcn_b     = (const float*)d_in[5];
    const float* cls_tok   = (const float*)d_in[6];
    const float* ln_pre_s  = (const float*)d_in[7];
    const float* ln_pre_b  = (const float*)d_in[8];
    const float* norm1_s   = (const float*)d_in[9];
    const float* norm1_b   = (const float*)d_in[10];
    const float* in_proj_w = (const float*)d_in[11];
    const float* in_proj_b = (const float*)d_in[12];
    const float* out_proj_w= (const float*)d_in[13];
    const float* out_proj_b= (const float*)d_in[14];
    const float* norm2_s   = (const float*)d_in[15];
    const float* norm2_b   = (const float*)d_in[16];
    const float* ff_w1     = (const float*)d_in[17];
    const float* ff_b1     = (const float*)d_in[18];
    const float* ff_w2     = (const float*)d_in[19];
    const float* ff_b2     = (const float*)d_in[20];
    const float* ln_post_s = (const float*)d_in[21];
    const float* ln_post_b = (const float*)d_in[22];
    const float* dec_w1    = (const float*)d_in[23];
    const float* dec_b1    = (const float*)d_in[24];
    const float* dec_w2    = (const float*)d_in[25];
    const float* dec_b2    = (const float*)d_in[26];
    const float* dec_w3    = (const float*)d_in[27];
    const float* dec_b3    = (const float*)d_in[28];

    float* ws   = (float*)d_ws;
    float* y    = ws + F_Y;
    float* agg  = ws + F_AGG;
    float* xd   = ws + F_XD;
    float* h1   = ws + F_H1;
    float* qkv  = ws + F_QKV;
    float* ffb  = ws + F_FFB;
    float* sc   = ffb;  // alias: scores live only while ffb is dead
    float* cls  = ws + F_CLS;
    float* dd1  = ws + F_D1;
    float* dd2  = ws + F_D2;
    float* wpad = ws + F_WPAD;
    float* dinv = ws + F_DINV;
    int* ibase  = (int*)(ws + F_END);
    int* indeg  = ibase;
    int* offs   = ibase + N_NODES;
    int* cursor = offs + N_NODES + 1;
    int* csr    = cursor + N_NODES;
    __bf16* wtb = (__bf16*)(csr + NEDGE);
    // bf16 transposed weights [N][K], per layer
    __bf16* wt_in  = wtb;                         // 2 x 768*256
    __bf16* wt_out = wt_in  + 2 * 768 * 256;      // 2 x 256*256
    __bf16* wt_f1  = wt_out + 2 * 256 * 256;      // 2 x 1024*256
    __bf16* wt_f2  = wt_f1  + 2 * 1024 * 256;     // 2 x 256*1024

    // GCN prelude
    hipMemsetAsync(indeg, 0, N_NODES * sizeof(int), stream);
    hist_kernel<<<NEDGE / 256, 256, 0, stream>>>(ei + NEDGE, indeg);
    scan_kernel<<<1, 1024, 0, stream>>>(indeg, offs, cursor, dinv);
    fill_kernel<<<NEDGE / 256, 256, 0, stream>>>(ei, cursor, csr);
    y_kernel<<<N_NODES * 64 / 256, 256, 0, stream>>>(x, p, dinv, y);
    agg_kernel<<<N_NODES / 4, 256, 0, stream>>>(y, dinv, offs, csr, agg);
    wpad_kernel<<<64, 256, 0, stream>>>(gcn_w, wpad);

    // weight transpose+cast (once per call)
    for (int l = 0; l < 2; ++l) {
        tcast_kernel<<<dim3(4, 12), 256, 0, stream>>>(in_proj_w + (size_t)l * 256 * 768,
                                                      wt_in + (size_t)l * 768 * 256, 256, 768);
        tcast_kernel<<<dim3(4, 4), 256, 0, stream>>>(out_proj_w + (size_t)l * 256 * 256,
                                                     wt_out + (size_t)l * 256 * 256, 256, 256);
        tcast_kernel<<<dim3(4, 16), 256, 0, stream>>>(ff_w1 + (size_t)l * 256 * 1024,
                                                      wt_f1 + (size_t)l * 1024 * 256, 256, 1024);
        tcast_kernel<<<dim3(16, 4), 256, 0, stream>>>(ff_w2 + (size_t)l * 1024 * 256,
                                                      wt_f2 + (size_t)l * 256 * 1024, 1024, 256);
    }

    // GCN matmul -> xd rows (remapped past cls slots), fp32
    gemm_std<0, false, true><<<dim3(256, 4), 256, 0, stream>>>(agg, 64, wpad, 256, gcn_b, xd, 256, 64);
    cls_write<<<64, 256, 0, stream>>>(cls_tok, xd);
    ln_kernel<<<MROWS, 256, 0, stream>>>(xd, xd, ln_pre_s, ln_pre_b, 1, 1);

    const int MB = (MROWS + 127) / 128;  // 129
    for (int l = 0; l < 2; ++l) {
        ln_kernel<<<MROWS, 256, 0, stream>>>(xd, h1, norm1_s + l * WDIM, norm1_b + l * WDIM, 1, 1);
        gemm_mfma<0, false><<<dim3(MB, 6), 256, 0, stream>>>(
            h1, 256, wt_in + (size_t)l * 768 * 256, in_proj_b + l * 768, qkv, 768, 256, MROWS);
        for (int c = 0; c < 4; ++c) {
            int b0 = c * 16;
            qk_kernel<<<dim3(5, 5, 128), 256, 0, stream>>>(qkv, sc, b0);
            softmax_kernel<<<(128 * SEQ) / 4, 256, 0, stream>>>(sc);
            pv_kernel<<<dim3(5, 128), 256, 0, stream>>>(sc, qkv, b0);
        }
        gemm_mfma<0, true><<<dim3(MB, 2), 256, 0, stream>>>(
            qkv, 768, wt_out + (size_t)l * 256 * 256, out_proj_b + l * WDIM, xd, 256, 256, MROWS);
        ln_kernel<<<MROWS, 256, 0, stream>>>(xd, h1, norm2_s + l * WDIM, norm2_b + l * WDIM, 1, 1);
        gemm_mfma<1, false><<<dim3(MB, 8), 256, 0, stream>>>(
            h1, 256, wt_f1 + (size_t)l * 1024 * 256, ff_b1 + l * DFF, ffb, 1024, 256, MROWS);
        gemm_mfma<1, true><<<dim3(MB, 2), 256, 0, stream>>>(
            ffb, 1024, wt_f2 + (size_t)l * 256 * 1024, ff_b2 + l * WDIM, xd, 256, 1024, MROWS);
    }

    // cls extract + ln_post + decoder
    ln_kernel<<<BGRAPH, 256, 0, stream>>>(xd, cls, ln_post_s, ln_post_b, SEQ, 1);
    dec_fc<<<BGRAPH, 256, 0, stream>>>(cls, dec_w1, dec_b1, dd1, 256, 512);
    dec_fc<<<BGRAPH, 256, 0, stream>>>(dd1, dec_w2, dec_b2, dd2, 512, 512);
    dec_fc<<<BGRAPH, 256, 0, stream>>>(dd2, dec_w3, dec_b3, (float*)d_out, 512, 64);
}